// Round 8
// baseline (178.476 us; speedup 1.0000x reference)
//
#include <hip/hip_runtime.h>
#include <math.h>

#define NH 12
#define DH 64
#define NSEQ 2048
#define NB 2
#define CDIM 768
#define NVIS 1536   // NSEQ - unseen_size(512)

typedef _Float16 half8 __attribute__((ext_vector_type(8)));
typedef _Float16 half4 __attribute__((ext_vector_type(4)));
typedef float floatx4 __attribute__((ext_vector_type(4)));

static constexpr size_t SZ_X    = (size_t)NB*NSEQ*CDIM;   // 3145728
static constexpr size_t SZ_WQKV = (size_t)3*CDIM*CDIM;    // 1769472
static constexpr size_t SZ_WP   = (size_t)CDIM*CDIM;      // 589824
static constexpr size_t SZ_HEAD = (size_t)NB*NH*NSEQ*DH;  // 3145728

#define GLOAD_LDS16(gp, lp) \
  __builtin_amdgcn_global_load_lds((const __attribute__((address_space(1))) void*)(gp), \
                                   (__attribute__((address_space(3))) void*)(lp), 16, 0, 0)

// ---------------- fp32 -> fp16 convert (x, w_qkv, w_proj) ----------------
__global__ __launch_bounds__(256) void convert_kernel(
    const float* __restrict__ x, const float* __restrict__ wqkv, const float* __restrict__ wp,
    _Float16* __restrict__ xb, _Float16* __restrict__ wqkvb, _Float16* __restrict__ wpb)
{
  size_t idx = ((size_t)blockIdx.x*256 + threadIdx.x)*4;
  const float* src; _Float16* dst; size_t off;
  if (idx < SZ_X)                        { src = x;    dst = xb;    off = idx; }
  else if (idx < SZ_X+SZ_WQKV)           { src = wqkv; dst = wqkvb; off = idx - SZ_X; }
  else if (idx < SZ_X+SZ_WQKV+SZ_WP)     { src = wp;   dst = wpb;   off = idx - SZ_X - SZ_WQKV; }
  else return;
  float4 v = *reinterpret_cast<const float4*>(src + off);
  _Float16 o[4] = {(_Float16)v.x,(_Float16)v.y,(_Float16)v.z,(_Float16)v.w};
  *reinterpret_cast<uint2*>(dst + off) = *reinterpret_cast<uint2*>(o);
}

// ---------------- GEMM: out[m,n] = sum_k A[m,k]*Bt[n,k]  (row-major, K=768) ---
// m97 structure: global_load_lds(16B) staging, BK=32 unpadded, XOR-chunk swizzle.
// MODE 0 (BN=128): q (pre-scaled 0.125*log2e), k epilogue; V^T via LDS transpose.
// MODE 1 (BN=128): fp32 out + bias.
template<int MODE, int BN>
__global__ __launch_bounds__(256) void gemm_bt(
    const _Float16* __restrict__ A, const _Float16* __restrict__ Bt,
    const float* __restrict__ bias,
    _Float16* __restrict__ qb, _Float16* __restrict__ kb, _Float16* __restrict__ vb,
    float* __restrict__ outp)
{
  constexpr int K = CDIM;
  constexpr int BM = 128, BK = 32;
  constexpr int MI = (BN == 128) ? 4 : 2;
  constexpr int NI = 4;
  constexpr int LDT = 132;                 // padded transpose stride (halves)
  constexpr int SMEM = (MODE == 0) ? 128*LDT : (BM*BK + BN*BK);
  __shared__ _Float16 smem[SMEM];
  _Float16* As = smem;
  _Float16* Bs = smem + BM*BK;
  const int tid = threadIdx.x;
  const int lane = tid & 63, wid = tid >> 6;
  const int l15 = lane & 15, quad = lane >> 4;
  const int wm = (BN == 128) ? (wid >> 1)*64 : wid*32;
  const int wn = (BN == 128) ? (wid & 1)*64 : 0;
  const int tileN = blockIdx.x*BN, tileM = blockIdx.y*BM;
  const int lrow = lane >> 2, lchunk = lane & 3;
  const int gcol = ((lchunk ^ (lrow >> 1)) & 3)*8;   // swizzled global col (halves)
  const _Float16* gA0 = A  + (size_t)(tileM + wid*32      + lrow)*K + gcol;
  const _Float16* gA1 = A  + (size_t)(tileM + wid*32 + 16 + lrow)*K + gcol;
  const _Float16* gB0 = Bt + (size_t)(tileN + ((BN==128) ? wid*32 : wid*16) + lrow)*K + gcol;
  const _Float16* gB1 = Bt + (size_t)(tileN + wid*32 + 16 + lrow)*K + gcol;  // BN=128 only
  _Float16* lA0 = As + (wid*32)*BK;
  _Float16* lA1 = As + (wid*32 + 16)*BK;
  _Float16* lB0 = Bs + ((BN==128) ? wid*32 : wid*16)*BK;
  _Float16* lB1 = Bs + (wid*32 + 16)*BK;
  const int cp = ((quad ^ (l15 >> 1)) & 3)*8;        // frag read chunk swizzle
  floatx4 acc[MI][NI] = {};
  for (int k0 = 0; k0 < K; k0 += BK) {
    __syncthreads();
    GLOAD_LDS16(gA0 + k0, lA0);
    GLOAD_LDS16(gA1 + k0, lA1);
    GLOAD_LDS16(gB0 + k0, lB0);
    if (BN == 128) GLOAD_LDS16(gB1 + k0, lB1);
    __syncthreads();
    half8 af[MI], bfr[NI];
    #pragma unroll
    for (int mi = 0; mi < MI; mi++)
      af[mi] = *reinterpret_cast<const half8*>(&As[(wm + mi*16 + l15)*BK + cp]);
    #pragma unroll
    for (int ni = 0; ni < NI; ni++)
      bfr[ni] = *reinterpret_cast<const half8*>(&Bs[(wn + ni*16 + l15)*BK + cp]);
    #pragma unroll
    for (int mi = 0; mi < MI; mi++)
      #pragma unroll
      for (int ni = 0; ni < NI; ni++)
        acc[mi][ni] = __builtin_amdgcn_mfma_f32_16x16x32_f16(af[mi], bfr[ni], acc[mi][ni], 0,0,0);
  }
  if (MODE == 0 && tileN >= 2*CDIM) {
    // ---- V^T epilogue: LDS transpose -> coalesced stores along kv ----
    __syncthreads();                       // K-loop LDS reads complete
    #pragma unroll
    for (int mi = 0; mi < MI; mi++)
      #pragma unroll
      for (int ni = 0; ni < NI; ni++) {
        int nl = wn + ni*16 + l15;         // local n (dd dim), 0..127
        int ml = wm + mi*16 + quad*4;      // local m (kv dim), rows r contiguous
        half4 pk = {(_Float16)acc[mi][ni][0], (_Float16)acc[mi][ni][1],
                    (_Float16)acc[mi][ni][2], (_Float16)acc[mi][ni][3]};
        *reinterpret_cast<half4*>(&smem[nl*LDT + ml]) = pk;
      }
    __syncthreads();
    const int b = tileM >> 11;             // block-uniform (BM | 2048)
    const int i0b = tileM & 2047;
    #pragma unroll
    for (int it = 0; it < 8; it++) {
      int row = it*16 + (tid >> 4);        // local n, 0..127
      int chunk = tid & 15;                // 16B chunk along kv
      int rem = tileN + row - 2*CDIM;
      int h = rem >> 6, dd = rem & 63;
      half8 v8 = *reinterpret_cast<const half8*>(&smem[row*LDT + chunk*8]);
      *reinterpret_cast<half8*>(&vb[(((size_t)b*NH + h)*DH + dd)*NSEQ + i0b + chunk*8]) = v8;
    }
    return;
  }
  #pragma unroll
  for (int mi = 0; mi < MI; mi++)
    #pragma unroll
    for (int ni = 0; ni < NI; ni++) {
      int n = tileN + wn + ni*16 + l15;
      int m0 = tileM + wm + mi*16 + quad*4;        // C-layout: row = quad*4+reg
      if (MODE == 0) {
        int part = n / CDIM, rem = n - part*CDIM;  // part in {0,1} here (v handled above)
        int h = rem >> 6, dd = rem & 63;
        int b = m0 >> 11, i0 = m0 & 2047;
        _Float16* dst = part ? kb : qb;
        float sc = part ? 1.0f : 0.125f*1.44269504f;  // fold scale+log2e into q
        #pragma unroll
        for (int r = 0; r < 4; r++)
          dst[(((size_t)b*NH + h)*NSEQ + i0 + r)*DH + dd] = (_Float16)(acc[mi][ni][r]*sc);
      } else {
        #pragma unroll
        for (int r = 0; r < 4; r++)
          outp[(size_t)(m0 + r)*CDIM + n] = acc[mi][ni][r] + bias[n];
      }
    }
}

// ---------------- flash attention: barrier-free chained-MFMA ------------------
// Round-7: the C-fragment of mfma_f32_16x16x32_f16 (S^T: row kv=quad*4+r,
// col q=l15) is EXACTLY the B-fragment of mfma_f32_16x16x16f16 (B[k=(l>>4)*4+j]
// [n=l&15]). So exp(S^T), packed to half4 in-register, feeds PV directly --
// no P LDS roundtrip, no inter-wave exchange, NO BARRIER in the loop (the
// barrier itself was the 45us floor; rounds 0-6 bracketed it). Wave w handles
// kv slice w*16..+16 of every tile vs ALL 64 d: A = V^T[d=dg*16+l15]
// [kv=w*16+quad*4+j] (half4 global loads, disjoint across waves -> zero
// intra-block load duplication, unlike round 3's failure). Partial O^T[64][64]
// accumulates in 64 VGPRs; one two-phase 32KB LDS reduction at the end merges
// the 4 wave partials. Per iter: 6 prefetched global loads, 8 K=32 + 16 K=16
// MFMA, ~50 VALU, zero LDS ops.
__global__ __launch_bounds__(256, 3) void fa_kernel(
    const _Float16* __restrict__ qg, const _Float16* __restrict__ kg,
    const _Float16* __restrict__ vtg, _Float16* __restrict__ og)
{
  __shared__ float Lo[4][64][32];    // 32KB reduction buffer (two d-phases)
  __shared__ float Ls[4][64];        // per-wave lsum partials
  __shared__ float Dinv[64];         // 1/den per q
  // XCD swizzle: all 32 q-tiles of one (b,h) on one XCD (24 bh = 8 xcd x 3)
  const int blk = blockIdx.x;
  const int idx = blk >> 3;                 // 0..95
  const int bh = (blk & 7)*3 + (idx % 3);   // 0..23
  const int qbase = (idx / 3) * 64;         // 0..1984
  const int tid = threadIdx.x;
  const int lane = tid & 63, w = tid >> 6;
  const int l15 = lane & 15, quad = lane >> 4;
  const _Float16* qp  = qg  + (size_t)bh*NSEQ*DH;
  const _Float16* kbp = kg  + (size_t)bh*NSEQ*DH;
  const _Float16* vbp = vtg + (size_t)bh*DH*NSEQ;
  // Q B-frags (n=q=g*16+l15, k=d=c*32+quad*8+j), resident; pre-scaled
  half8 qf[4][2];
  #pragma unroll
  for (int g = 0; g < 4; g++)
    #pragma unroll
    for (int c = 0; c < 2; c++)
      qf[g][c] = *reinterpret_cast<const half8*>(qp + (size_t)(qbase + g*16 + l15)*DH + c*32 + quad*8);
  // K rows kv = w*16 + l15 (A-frag of S^T, k=d=quad*8+j)
  const _Float16* kRow = kbp + (size_t)(w*16 + l15)*DH + quad*8;
  // V^T A-frag (16x16x16): A[m=d_loc=l15][k=kv=w*16+quad*4+j]
  const _Float16* vA = vbp + (size_t)l15*NSEQ + w*16 + quad*4;

  floatx4 o[4][4] = {};   // o[dg][g]: O^T[d=dg*16+quad*4+r][q=g*16+l15] partial (wave's kv)
  float lsum[4] = {0.f, 0.f, 0.f, 0.f};

  half8 kc0 = *reinterpret_cast<const half8*>(kRow);
  half8 kc1 = *reinterpret_cast<const half8*>(kRow + 32);
  half4 vc[4];
  #pragma unroll
  for (int dg = 0; dg < 4; dg++)
    vc[dg] = *reinterpret_cast<const half4*>(vA + (size_t)dg*16*NSEQ);

  for (int t = 0; t < 24; t++) {
    // prefetch tile t+1 (t=23 -> rows/cols 1536+, in-bounds, unused)
    const _Float16* kn = kRow + (size_t)(t+1)*64*DH;
    half8 kn0 = *reinterpret_cast<const half8*>(kn);
    half8 kn1 = *reinterpret_cast<const half8*>(kn + 32);
    half4 vn[4];
    #pragma unroll
    for (int dg = 0; dg < 4; dg++)
      vn[dg] = *reinterpret_cast<const half4*>(vA + (size_t)dg*16*NSEQ + (t+1)*64);
    // S^T(t): st[g] row kv=w*16+quad*4+r, col q=g*16+l15
    floatx4 st[4] = {};
    __builtin_amdgcn_s_setprio(1);
    #pragma unroll
    for (int g = 0; g < 4; g++) {
      st[g] = __builtin_amdgcn_mfma_f32_16x16x32_f16(kc0, qf[g][0], st[g], 0,0,0);
      st[g] = __builtin_amdgcn_mfma_f32_16x16x32_f16(kc1, qf[g][1], st[g], 0,0,0);
    }
    __builtin_amdgcn_s_setprio(0);
    // exp + in-register pack: P C-frag == B-frag of 16x16x16f16
    half4 pk4[4];
    #pragma unroll
    for (int g = 0; g < 4; g++) {
      float e0 = __builtin_exp2f(st[g][0]), e1 = __builtin_exp2f(st[g][1]);
      float e2 = __builtin_exp2f(st[g][2]), e3 = __builtin_exp2f(st[g][3]);
      lsum[g] += (e0+e1)+(e2+e3);
      pk4[g] = half4{(_Float16)e0,(_Float16)e1,(_Float16)e2,(_Float16)e3};
    }
    // PV(t): o[dg][g] += V^T[dg][wave's kv16] * P[wave's kv16][g]
    __builtin_amdgcn_s_setprio(1);
    #pragma unroll
    for (int dg = 0; dg < 4; dg++)
      #pragma unroll
      for (int g = 0; g < 4; g++)
        o[dg][g] = __builtin_amdgcn_mfma_f32_16x16x16f16(vc[dg], pk4[g], o[dg][g], 0,0,0);
    __builtin_amdgcn_s_setprio(0);
    kc0 = kn0; kc1 = kn1;
    #pragma unroll
    for (int dg = 0; dg < 4; dg++) vc[dg] = vn[dg];
  }

  // lsum: cross-quad (wave covers kv=w*16+quad*4+r), then cross-wave via LDS
  #pragma unroll
  for (int g = 0; g < 4; g++) {
    lsum[g] += __shfl_xor(lsum[g], 16);
    lsum[g] += __shfl_xor(lsum[g], 32);
  }
  if (lane < 16) {
    #pragma unroll
    for (int g = 0; g < 4; g++) Ls[w][g*16 + lane] = lsum[g];
  }
  __syncthreads();
  float den[4];
  #pragma unroll
  for (int g = 0; g < 4; g++)
    den[g] = Ls[0][g*16+l15] + Ls[1][g*16+l15] + Ls[2][g*16+l15] + Ls[3][g*16+l15];
  // peeled diagonal term for unseen rows: wave w adds O-part into o[dg==w]
  // (any single wave suffices -- partials are summed); den add is per-lane copy.
  if (qbase >= NVIS) {
    #pragma unroll
    for (int g = 0; g < 4; g++) {
      const int qrow = qbase + g*16 + l15;
      half8 kd0 = *reinterpret_cast<const half8*>(kbp + (size_t)qrow*DH + quad*8);
      half8 kd1 = *reinterpret_cast<const half8*>(kbp + (size_t)qrow*DH + 32 + quad*8);
      float pd = 0.f;
      #pragma unroll
      for (int j = 0; j < 8; j++)
        pd += (float)qf[g][0][j]*(float)kd0[j] + (float)qf[g][1][j]*(float)kd1[j];
      pd += __shfl_xor(pd, 16);
      pd += __shfl_xor(pd, 32);
      float e = __builtin_exp2f(pd);
      den[g] += e;
      #pragma unroll
      for (int dg = 0; dg < 4; dg++)
        if (dg == w)     // static index into o (rule 20), wave-uniform guard
          #pragma unroll
          for (int r = 0; r < 4; r++)
            o[dg][g][r] += e * (float)vbp[(size_t)(dg*16 + quad*4 + r)*NSEQ + qrow];
    }
  }
  if (tid < 16) {
    #pragma unroll
    for (int g = 0; g < 4; g++) Dinv[g*16 + tid] = 1.0f / den[g];
  }
  const int b = bh / NH, h = bh - b*NH;
  // two-phase cross-wave O reduction: phase hf covers d = hf*32 .. +32
  const int rq = tid >> 2, rc = tid & 3, rkey = rq & 7;
  #pragma unroll
  for (int hf = 0; hf < 2; hf++) {
    __syncthreads();   // phase 0: Dinv/Ls done; phase 1: prior reads done
    #pragma unroll
    for (int dgl = 0; dgl < 2; dgl++)
      #pragma unroll
      for (int g = 0; g < 4; g++) {
        int gl = (dgl*4 + quad) ^ (l15 & 7);   // 16B-granule XOR swizzle
        *reinterpret_cast<floatx4*>(&Lo[w][g*16 + l15][gl*4]) = o[hf*2 + dgl][g];
      }
    __syncthreads();
    float acc[8] = {0.f,0.f,0.f,0.f,0.f,0.f,0.f,0.f};
    #pragma unroll
    for (int wv = 0; wv < 4; wv++)
      #pragma unroll
      for (int j = 0; j < 2; j++) {
        int gp = (rc*2 + j) ^ rkey;
        floatx4 v = *reinterpret_cast<const floatx4*>(&Lo[wv][rq][gp*4]);
        acc[j*4+0] += v[0]; acc[j*4+1] += v[1];
        acc[j*4+2] += v[2]; acc[j*4+3] += v[3];
      }
    float inv = Dinv[rq];
    half8 outv;
    #pragma unroll
    for (int i = 0; i < 8; i++) outv[i] = (_Float16)(acc[i]*inv);
    *reinterpret_cast<half8*>(
      &og[((size_t)b*NSEQ + qbase + rq)*CDIM + h*DH + hf*32 + rc*8]) = outv;
  }
}

extern "C" void kernel_launch(void* const* d_in, const int* in_sizes, int n_in,
                              void* d_out, int out_size, void* d_ws, size_t ws_size,
                              hipStream_t stream) {
  (void)in_sizes; (void)n_in; (void)out_size; (void)ws_size;
  const float* x     = (const float*)d_in[0];
  const float* wqkv  = (const float*)d_in[1];
  const float* wproj = (const float*)d_in[2];
  const float* bproj = (const float*)d_in[3];
  // d_in[4] = unseen_size (512, compile-time constant NVIS)

  _Float16* xb    = (_Float16*)d_ws;
  _Float16* wqkvb = xb + SZ_X;
  _Float16* wpb   = wqkvb + SZ_WQKV;
  _Float16* qb    = wpb + SZ_WP;
  _Float16* kb    = qb + SZ_HEAD;
  _Float16* vb    = kb + SZ_HEAD;   // holds V^T [b,h,d,kv]
  _Float16* ob    = vb + SZ_HEAD;
  float* outp = (float*)d_out;

  size_t total = SZ_X + SZ_WQKV + SZ_WP;
  int cblocks = (int)((total/4 + 255)/256);
  convert_kernel<<<cblocks, 256, 0, stream>>>(x, wqkv, wproj, xb, wqkvb, wpb);
  gemm_bt<0,128><<<dim3(3*CDIM/128, NB*NSEQ/128), 256, 0, stream>>>(xb, wqkvb, nullptr, qb, kb, vb, nullptr);
  fa_kernel<<<NB*NH*(NSEQ/64), 256, 0, stream>>>(qb, kb, vb, ob);
  gemm_bt<1,128><<<dim3(CDIM/128, NB*NSEQ/128), 256, 0, stream>>>(ob, wpb, bproj, nullptr, nullptr, nullptr, outp);
}

// Round 9
// 163.464 us; speedup vs baseline: 1.0918x; 1.0918x over previous
//
#include <hip/hip_runtime.h>
#include <math.h>

#define NH 12
#define DH 64
#define NSEQ 2048
#define NB 2
#define CDIM 768
#define NVIS 1536   // NSEQ - unseen_size(512)

typedef _Float16 half8 __attribute__((ext_vector_type(8)));
typedef _Float16 half4 __attribute__((ext_vector_type(4)));
typedef float floatx4 __attribute__((ext_vector_type(4)));

static constexpr size_t SZ_X    = (size_t)NB*NSEQ*CDIM;   // 3145728
static constexpr size_t SZ_WQKV = (size_t)3*CDIM*CDIM;    // 1769472
static constexpr size_t SZ_WP   = (size_t)CDIM*CDIM;      // 589824
static constexpr size_t SZ_HEAD = (size_t)NB*NH*NSEQ*DH;  // 3145728

#define GLOAD_LDS16(gp, lp) \
  __builtin_amdgcn_global_load_lds((const __attribute__((address_space(1))) void*)(gp), \
                                   (__attribute__((address_space(3))) void*)(lp), 16, 0, 0)

// ---------------- fp32 -> fp16 convert (x, w_qkv, w_proj) ----------------
__global__ __launch_bounds__(256) void convert_kernel(
    const float* __restrict__ x, const float* __restrict__ wqkv, const float* __restrict__ wp,
    _Float16* __restrict__ xb, _Float16* __restrict__ wqkvb, _Float16* __restrict__ wpb)
{
  size_t idx = ((size_t)blockIdx.x*256 + threadIdx.x)*4;
  const float* src; _Float16* dst; size_t off;
  if (idx < SZ_X)                        { src = x;    dst = xb;    off = idx; }
  else if (idx < SZ_X+SZ_WQKV)           { src = wqkv; dst = wqkvb; off = idx - SZ_X; }
  else if (idx < SZ_X+SZ_WQKV+SZ_WP)     { src = wp;   dst = wpb;   off = idx - SZ_X - SZ_WQKV; }
  else return;
  float4 v = *reinterpret_cast<const float4*>(src + off);
  _Float16 o[4] = {(_Float16)v.x,(_Float16)v.y,(_Float16)v.z,(_Float16)v.w};
  *reinterpret_cast<uint2*>(dst + off) = *reinterpret_cast<uint2*>(o);
}

// ---------------- GEMM: out[m,n] = sum_k A[m,k]*Bt[n,k]  (row-major, K=768) ---
// m97 structure: global_load_lds(16B) staging, BK=32 unpadded, XOR-chunk swizzle.
// MODE 0 (BN=128): q (pre-scaled 0.125*log2e), k epilogue; V^T via LDS transpose.
// MODE 1 (BN=128): fp32 out + bias.
template<int MODE, int BN>
__global__ __launch_bounds__(256) void gemm_bt(
    const _Float16* __restrict__ A, const _Float16* __restrict__ Bt,
    const float* __restrict__ bias,
    _Float16* __restrict__ qb, _Float16* __restrict__ kb, _Float16* __restrict__ vb,
    float* __restrict__ outp)
{
  constexpr int K = CDIM;
  constexpr int BM = 128, BK = 32;
  constexpr int MI = (BN == 128) ? 4 : 2;
  constexpr int NI = 4;
  constexpr int LDT = 132;                 // padded transpose stride (halves)
  constexpr int SMEM = (MODE == 0) ? 128*LDT : (BM*BK + BN*BK);
  __shared__ _Float16 smem[SMEM];
  _Float16* As = smem;
  _Float16* Bs = smem + BM*BK;
  const int tid = threadIdx.x;
  const int lane = tid & 63, wid = tid >> 6;
  const int l15 = lane & 15, quad = lane >> 4;
  const int wm = (BN == 128) ? (wid >> 1)*64 : wid*32;
  const int wn = (BN == 128) ? (wid & 1)*64 : 0;
  const int tileN = blockIdx.x*BN, tileM = blockIdx.y*BM;
  const int lrow = lane >> 2, lchunk = lane & 3;
  const int gcol = ((lchunk ^ (lrow >> 1)) & 3)*8;   // swizzled global col (halves)
  const _Float16* gA0 = A  + (size_t)(tileM + wid*32      + lrow)*K + gcol;
  const _Float16* gA1 = A  + (size_t)(tileM + wid*32 + 16 + lrow)*K + gcol;
  const _Float16* gB0 = Bt + (size_t)(tileN + ((BN==128) ? wid*32 : wid*16) + lrow)*K + gcol;
  const _Float16* gB1 = Bt + (size_t)(tileN + wid*32 + 16 + lrow)*K + gcol;  // BN=128 only
  _Float16* lA0 = As + (wid*32)*BK;
  _Float16* lA1 = As + (wid*32 + 16)*BK;
  _Float16* lB0 = Bs + ((BN==128) ? wid*32 : wid*16)*BK;
  _Float16* lB1 = Bs + (wid*32 + 16)*BK;
  const int cp = ((quad ^ (l15 >> 1)) & 3)*8;        // frag read chunk swizzle
  floatx4 acc[MI][NI] = {};
  for (int k0 = 0; k0 < K; k0 += BK) {
    __syncthreads();
    GLOAD_LDS16(gA0 + k0, lA0);
    GLOAD_LDS16(gA1 + k0, lA1);
    GLOAD_LDS16(gB0 + k0, lB0);
    if (BN == 128) GLOAD_LDS16(gB1 + k0, lB1);
    __syncthreads();
    half8 af[MI], bfr[NI];
    #pragma unroll
    for (int mi = 0; mi < MI; mi++)
      af[mi] = *reinterpret_cast<const half8*>(&As[(wm + mi*16 + l15)*BK + cp]);
    #pragma unroll
    for (int ni = 0; ni < NI; ni++)
      bfr[ni] = *reinterpret_cast<const half8*>(&Bs[(wn + ni*16 + l15)*BK + cp]);
    #pragma unroll
    for (int mi = 0; mi < MI; mi++)
      #pragma unroll
      for (int ni = 0; ni < NI; ni++)
        acc[mi][ni] = __builtin_amdgcn_mfma_f32_16x16x32_f16(af[mi], bfr[ni], acc[mi][ni], 0,0,0);
  }
  if (MODE == 0 && tileN >= 2*CDIM) {
    // ---- V^T epilogue: LDS transpose -> coalesced stores along kv ----
    __syncthreads();                       // K-loop LDS reads complete
    #pragma unroll
    for (int mi = 0; mi < MI; mi++)
      #pragma unroll
      for (int ni = 0; ni < NI; ni++) {
        int nl = wn + ni*16 + l15;         // local n (dd dim), 0..127
        int ml = wm + mi*16 + quad*4;      // local m (kv dim), rows r contiguous
        half4 pk = {(_Float16)acc[mi][ni][0], (_Float16)acc[mi][ni][1],
                    (_Float16)acc[mi][ni][2], (_Float16)acc[mi][ni][3]};
        *reinterpret_cast<half4*>(&smem[nl*LDT + ml]) = pk;
      }
    __syncthreads();
    const int b = tileM >> 11;             // block-uniform (BM | 2048)
    const int i0b = tileM & 2047;
    #pragma unroll
    for (int it = 0; it < 8; it++) {
      int row = it*16 + (tid >> 4);        // local n, 0..127
      int chunk = tid & 15;                // 16B chunk along kv
      int rem = tileN + row - 2*CDIM;
      int h = rem >> 6, dd = rem & 63;
      half8 v8 = *reinterpret_cast<const half8*>(&smem[row*LDT + chunk*8]);
      *reinterpret_cast<half8*>(&vb[(((size_t)b*NH + h)*DH + dd)*NSEQ + i0b + chunk*8]) = v8;
    }
    return;
  }
  #pragma unroll
  for (int mi = 0; mi < MI; mi++)
    #pragma unroll
    for (int ni = 0; ni < NI; ni++) {
      int n = tileN + wn + ni*16 + l15;
      int m0 = tileM + wm + mi*16 + quad*4;        // C-layout: row = quad*4+reg
      if (MODE == 0) {
        int part = n / CDIM, rem = n - part*CDIM;  // part in {0,1} here (v handled above)
        int h = rem >> 6, dd = rem & 63;
        int b = m0 >> 11, i0 = m0 & 2047;
        _Float16* dst = part ? kb : qb;
        float sc = part ? 1.0f : 0.125f*1.44269504f;  // fold scale+log2e into q
        #pragma unroll
        for (int r = 0; r < 4; r++)
          dst[(((size_t)b*NH + h)*NSEQ + i0 + r)*DH + dd] = (_Float16)(acc[mi][ni][r]*sc);
      } else {
        #pragma unroll
        for (int r = 0; r < 4; r++)
          outp[(size_t)(m0 + r)*CDIM + n] = acc[mi][ni][r] + bias[n];
      }
    }
}

// ---------------- flash attention: round-1 structure, KVBLK=128 ---------------
// Round-8: rounds 1/2 measured the scaling law (fixed cost F~2.5-3.5k cy per
// barrier-iteration vs work W~1.5-2k cy): halving W/barrier halved efficiency.
// Invert it: 128 kv per iteration -> 12 barriers instead of 24, same total
// MFMA/exp work. Wave w owns kv rows w*32..+32 (two 16-row groups) for S^T;
// PV unchanged (d rows w*16..+16, 4 K=32 chunks per q-group). P LDS [64][128]
// double-buffered (32KB) with the XOR swizzle applied within each 64-col half
// (phys = (kv&64) | ((kv&63)^sw)). Everything else identical to the verified
// 48.3us round-1 kernel: pipelined P, post-barrier prefetch, setprio,
// wave-private lsum + LDS reduce, peeled diagonal.
__global__ __launch_bounds__(256, 3) void fa_kernel(
    const _Float16* __restrict__ qg, const _Float16* __restrict__ kg,
    const _Float16* __restrict__ vtg, _Float16* __restrict__ og)
{
  __shared__ _Float16 Ps[2][64*128]; // double-buffered P[q][kv128], XOR-swizzled
  __shared__ float Ls[4*64];         // per-wave lsum partials
  // XCD swizzle: all 32 q-tiles of one (b,h) on one XCD (24 bh = 8 xcd x 3)
  const int blk = blockIdx.x;
  const int idx = blk >> 3;                 // 0..95
  const int bh = (blk & 7)*3 + (idx % 3);   // 0..23
  const int qbase = (idx / 3) * 64;         // 0..1984
  const int tid = threadIdx.x;
  const int lane = tid & 63, w = tid >> 6;
  const int l15 = lane & 15, quad = lane >> 4;
  const int sw = (l15 & 7) << 3;            // P swizzle key (half units)
  const _Float16* qp  = qg  + (size_t)bh*NSEQ*DH;
  const _Float16* kbp = kg  + (size_t)bh*NSEQ*DH;
  const _Float16* vbp = vtg + (size_t)bh*DH*NSEQ;
  // Q B-frags (n=q=g*16+l15, k=d=c*32+quad*8+j), resident; pre-scaled
  half8 qf[4][2];
  #pragma unroll
  for (int g = 0; g < 4; g++)
    #pragma unroll
    for (int c = 0; c < 2; c++)
      qf[g][c] = *reinterpret_cast<const half8*>(qp + (size_t)(qbase + g*16 + l15)*DH + c*32 + quad*8);
  // K rows: s=0 -> kv=w*32+l15, s=1 -> kv=w*32+16+l15 (A-frag, k=d=quad*8+j)
  const _Float16* kR0 = kbp + (size_t)(w*32      + l15)*DH + quad*8;
  const _Float16* kR1 = kbp + (size_t)(w*32 + 16 + l15)*DH + quad*8;
  // V^T rows d=w*16+l15 (A-frag, k=kv chunk c*32+quad*8+j)
  const _Float16* vRow = vbp + (size_t)(w*16 + l15)*NSEQ + quad*8;
  floatx4 o[4] = {};                 // O^T: row d=w*16+quad*4+r, col q=g*16+l15
  float lsum[4] = {0.f, 0.f, 0.f, 0.f};
  // P store cols (swizzled within 64-col halves)
  const int x0 = w*32      + quad*4;
  const int x1 = w*32 + 16 + quad*4;
  const int pws0 = (x0 & 64) | ((x0 & 63) ^ sw);
  const int pws1 = (x1 & 64) | ((x1 & 63) ^ sw);
  // P read cols, chunks c=0..3
  const int prd0 = (quad*8) ^ sw;
  const int prd1 = (32 + quad*8) ^ sw;
  const int prd2 = 64 | prd0;
  const int prd3 = 64 | prd1;

  // --- prologue: S(0) -> P(0) into buf0; vc(0); kc(1) ---
  half8 kc00 = *reinterpret_cast<const half8*>(kR0);
  half8 kc01 = *reinterpret_cast<const half8*>(kR0 + 32);
  half8 kc10 = *reinterpret_cast<const half8*>(kR1);
  half8 kc11 = *reinterpret_cast<const half8*>(kR1 + 32);
  {
    floatx4 st0[4] = {}, st1[4] = {};
    #pragma unroll
    for (int g = 0; g < 4; g++) {
      st0[g] = __builtin_amdgcn_mfma_f32_16x16x32_f16(kc00, qf[g][0], st0[g], 0,0,0);
      st0[g] = __builtin_amdgcn_mfma_f32_16x16x32_f16(kc01, qf[g][1], st0[g], 0,0,0);
      st1[g] = __builtin_amdgcn_mfma_f32_16x16x32_f16(kc10, qf[g][0], st1[g], 0,0,0);
      st1[g] = __builtin_amdgcn_mfma_f32_16x16x32_f16(kc11, qf[g][1], st1[g], 0,0,0);
    }
    #pragma unroll
    for (int g = 0; g < 4; g++) {
      float e0 = __builtin_exp2f(st0[g][0]), e1 = __builtin_exp2f(st0[g][1]);
      float e2 = __builtin_exp2f(st0[g][2]), e3 = __builtin_exp2f(st0[g][3]);
      float f0 = __builtin_exp2f(st1[g][0]), f1 = __builtin_exp2f(st1[g][1]);
      float f2 = __builtin_exp2f(st1[g][2]), f3 = __builtin_exp2f(st1[g][3]);
      lsum[g] += ((e0+e1)+(e2+e3)) + ((f0+f1)+(f2+f3));
      *reinterpret_cast<half4*>(&Ps[0][(g*16+l15)*128 + pws0]) =
        half4{(_Float16)e0,(_Float16)e1,(_Float16)e2,(_Float16)e3};
      *reinterpret_cast<half4*>(&Ps[0][(g*16+l15)*128 + pws1]) =
        half4{(_Float16)f0,(_Float16)f1,(_Float16)f2,(_Float16)f3};
    }
  }
  half8 vc0 = *reinterpret_cast<const half8*>(vRow);
  half8 vc1 = *reinterpret_cast<const half8*>(vRow + 32);
  half8 vc2 = *reinterpret_cast<const half8*>(vRow + 64);
  half8 vc3 = *reinterpret_cast<const half8*>(vRow + 96);
  kc00 = *reinterpret_cast<const half8*>(kR0 + (size_t)128*DH);
  kc01 = *reinterpret_cast<const half8*>(kR0 + (size_t)128*DH + 32);
  kc10 = *reinterpret_cast<const half8*>(kR1 + (size_t)128*DH);
  kc11 = *reinterpret_cast<const half8*>(kR1 + (size_t)128*DH + 32);

  // --- main loop: iter t does S(t+1) + barrier + {prefetch, P(t+1), PV(t)} ---
  for (int t = 0; t < 11; t++) {
    // S(t+1): two 16-row kv groups
    floatx4 st0[4] = {}, st1[4] = {};
    __builtin_amdgcn_s_setprio(1);
    #pragma unroll
    for (int g = 0; g < 4; g++) {
      st0[g] = __builtin_amdgcn_mfma_f32_16x16x32_f16(kc00, qf[g][0], st0[g], 0,0,0);
      st0[g] = __builtin_amdgcn_mfma_f32_16x16x32_f16(kc01, qf[g][1], st0[g], 0,0,0);
      st1[g] = __builtin_amdgcn_mfma_f32_16x16x32_f16(kc10, qf[g][0], st1[g], 0,0,0);
      st1[g] = __builtin_amdgcn_mfma_f32_16x16x32_f16(kc11, qf[g][1], st1[g], 0,0,0);
    }
    __builtin_amdgcn_s_setprio(0);
    half4 pk0[4], pk1[4];
    #pragma unroll
    for (int g = 0; g < 4; g++) {
      float e0 = __builtin_exp2f(st0[g][0]), e1 = __builtin_exp2f(st0[g][1]);
      float e2 = __builtin_exp2f(st0[g][2]), e3 = __builtin_exp2f(st0[g][3]);
      float f0 = __builtin_exp2f(st1[g][0]), f1 = __builtin_exp2f(st1[g][1]);
      float f2 = __builtin_exp2f(st1[g][2]), f3 = __builtin_exp2f(st1[g][3]);
      lsum[g] += ((e0+e1)+(e2+e3)) + ((f0+f1)+(f2+f3));
      pk0[g] = half4{(_Float16)e0,(_Float16)e1,(_Float16)e2,(_Float16)e3};
      pk1[g] = half4{(_Float16)f0,(_Float16)f1,(_Float16)f2,(_Float16)f3};
    }
    __syncthreads();  // P(t) visible; Ps[(t+1)&1] readers (iter t-1) done
    // prefetch kc(t+2), vc(t+1) post-barrier (private, TLP-hideable)
    half8 kn00 = *reinterpret_cast<const half8*>(kR0 + (size_t)(t+2)*128*DH);
    half8 kn01 = *reinterpret_cast<const half8*>(kR0 + (size_t)(t+2)*128*DH + 32);
    half8 kn10 = *reinterpret_cast<const half8*>(kR1 + (size_t)(t+2)*128*DH);
    half8 kn11 = *reinterpret_cast<const half8*>(kR1 + (size_t)(t+2)*128*DH + 32);
    half8 vn0 = *reinterpret_cast<const half8*>(vRow + (t+1)*128);
    half8 vn1 = *reinterpret_cast<const half8*>(vRow + (t+1)*128 + 32);
    half8 vn2 = *reinterpret_cast<const half8*>(vRow + (t+1)*128 + 64);
    half8 vn3 = *reinterpret_cast<const half8*>(vRow + (t+1)*128 + 96);
    #pragma unroll
    for (int g = 0; g < 4; g++) {
      *reinterpret_cast<half4*>(&Ps[(t+1)&1][(g*16+l15)*128 + pws0]) = pk0[g];
      *reinterpret_cast<half4*>(&Ps[(t+1)&1][(g*16+l15)*128 + pws1]) = pk1[g];
    }
    // PV(t) from Ps[t&1]: 4 chunks of K=32 per q-group
    __builtin_amdgcn_s_setprio(1);
    #pragma unroll
    for (int g = 0; g < 4; g++) {
      const _Float16* pb = &Ps[t&1][(g*16+l15)*128];
      half8 b0 = *reinterpret_cast<const half8*>(pb + prd0);
      half8 b1 = *reinterpret_cast<const half8*>(pb + prd1);
      half8 b2 = *reinterpret_cast<const half8*>(pb + prd2);
      half8 b3 = *reinterpret_cast<const half8*>(pb + prd3);
      o[g] = __builtin_amdgcn_mfma_f32_16x16x32_f16(vc0, b0, o[g], 0,0,0);
      o[g] = __builtin_amdgcn_mfma_f32_16x16x32_f16(vc1, b1, o[g], 0,0,0);
      o[g] = __builtin_amdgcn_mfma_f32_16x16x32_f16(vc2, b2, o[g], 0,0,0);
      o[g] = __builtin_amdgcn_mfma_f32_16x16x32_f16(vc3, b3, o[g], 0,0,0);
    }
    __builtin_amdgcn_s_setprio(0);
    kc00 = kn00; kc01 = kn01; kc10 = kn10; kc11 = kn11;
    vc0 = vn0; vc1 = vn1; vc2 = vn2; vc3 = vn3;
  }
  // --- epilogue: PV(11) from Ps[1] ---
  __syncthreads();
  #pragma unroll
  for (int g = 0; g < 4; g++) {
    const _Float16* pb = &Ps[1][(g*16+l15)*128];
    half8 b0 = *reinterpret_cast<const half8*>(pb + prd0);
    half8 b1 = *reinterpret_cast<const half8*>(pb + prd1);
    half8 b2 = *reinterpret_cast<const half8*>(pb + prd2);
    half8 b3 = *reinterpret_cast<const half8*>(pb + prd3);
    o[g] = __builtin_amdgcn_mfma_f32_16x16x32_f16(vc0, b0, o[g], 0,0,0);
    o[g] = __builtin_amdgcn_mfma_f32_16x16x32_f16(vc1, b1, o[g], 0,0,0);
    o[g] = __builtin_amdgcn_mfma_f32_16x16x32_f16(vc2, b2, o[g], 0,0,0);
    o[g] = __builtin_amdgcn_mfma_f32_16x16x32_f16(vc3, b3, o[g], 0,0,0);
  }
  // lsum: cross-quad, then cross-wave via LDS
  #pragma unroll
  for (int g = 0; g < 4; g++) {
    lsum[g] += __shfl_xor(lsum[g], 16);
    lsum[g] += __shfl_xor(lsum[g], 32);
  }
  if (lane < 16) {
    #pragma unroll
    for (int g = 0; g < 4; g++) Ls[w*64 + g*16 + lane] = lsum[g];
  }
  __syncthreads();
  float den[4];
  #pragma unroll
  for (int g = 0; g < 4; g++)
    den[g] = Ls[g*16+l15] + Ls[64+g*16+l15] + Ls[128+g*16+l15] + Ls[192+g*16+l15];
  // peeled diagonal term for unseen rows
  if (qbase >= NVIS) {
    #pragma unroll
    for (int g = 0; g < 4; g++) {
      half8 kd0 = *reinterpret_cast<const half8*>(kbp + (size_t)(qbase + g*16 + l15)*DH + quad*8);
      half8 kd1 = *reinterpret_cast<const half8*>(kbp + (size_t)(qbase + g*16 + l15)*DH + 32 + quad*8);
      float pd = 0.f;
      #pragma unroll
      for (int j = 0; j < 8; j++)
        pd += (float)qf[g][0][j]*(float)kd0[j] + (float)qf[g][1][j]*(float)kd1[j];
      pd += __shfl_xor(pd, 16);
      pd += __shfl_xor(pd, 32);
      float e = __builtin_exp2f(pd);
      den[g] += e;
      #pragma unroll
      for (int r = 0; r < 4; r++)
        o[g][r] += e * (float)vbp[(size_t)(w*16+quad*4+r)*NSEQ + qbase + g*16 + l15];
    }
  }
  const int b = bh / NH, h = bh - b*NH;
  #pragma unroll
  for (int g = 0; g < 4; g++) {
    float inv = 1.0f / den[g];
    half4 pk = {(_Float16)(o[g][0]*inv), (_Float16)(o[g][1]*inv),
                (_Float16)(o[g][2]*inv), (_Float16)(o[g][3]*inv)};
    size_t oaddr = ((size_t)b*NSEQ + qbase + g*16 + l15)*CDIM + h*DH + w*16 + quad*4;
    *reinterpret_cast<half4*>(&og[oaddr]) = pk;
  }
}

extern "C" void kernel_launch(void* const* d_in, const int* in_sizes, int n_in,
                              void* d_out, int out_size, void* d_ws, size_t ws_size,
                              hipStream_t stream) {
  (void)in_sizes; (void)n_in; (void)out_size; (void)ws_size;
  const float* x     = (const float*)d_in[0];
  const float* wqkv  = (const float*)d_in[1];
  const float* wproj = (const float*)d_in[2];
  const float* bproj = (const float*)d_in[3];
  // d_in[4] = unseen_size (512, compile-time constant NVIS)

  _Float16* xb    = (_Float16*)d_ws;
  _Float16* wqkvb = xb + SZ_X;
  _Float16* wpb   = wqkvb + SZ_WQKV;
  _Float16* qb    = wpb + SZ_WP;
  _Float16* kb    = qb + SZ_HEAD;
  _Float16* vb    = kb + SZ_HEAD;   // holds V^T [b,h,d,kv]
  _Float16* ob    = vb + SZ_HEAD;
  float* outp = (float*)d_out;

  size_t total = SZ_X + SZ_WQKV + SZ_WP;
  int cblocks = (int)((total/4 + 255)/256);
  convert_kernel<<<cblocks, 256, 0, stream>>>(x, wqkv, wproj, xb, wqkvb, wpb);
  gemm_bt<0,128><<<dim3(3*CDIM/128, NB*NSEQ/128), 256, 0, stream>>>(xb, wqkvb, nullptr, qb, kb, vb, nullptr);
  fa_kernel<<<NB*NH*(NSEQ/64), 256, 0, stream>>>(qb, kb, vb, ob);
  gemm_bt<1,128><<<dim3(CDIM/128, NB*NSEQ/128), 256, 0, stream>>>(ob, wpb, bproj, nullptr, nullptr, nullptr, outp);
}